// Round 6
// baseline (104.646 us; speedup 1.0000x reference)
//
#include <hip/hip_runtime.h>
#include <stdint.h>

// Problem constants (match reference)
#define NFEAT 3072          // C*H*W
#define NWORD 2             // 128 batch bits / 64
#define NK 64               // kernels
#define NP 784              // output positions
#define NG 8                // level-0 gates per (k,p)
#define KP (NK * NP)        // 50176
#define NL1 64000
#define NL2 32000
#define NCLS 10
#define NB 128              // batch
#define JBLK 128            // j's per lin2 block; 3200 % 128 == 0

// Truth-table gate. op bit0 -> (a=1,b=1), bit1 -> (a=1,b=0), bit2 -> (a=0,b=1),
// bit3 -> (a=0,b=0). Verified against ALL 16 COEF rows: the op index's binary
// representation IS the truth table (op1=AND=0001, op6=XOR=0110, op8=NOR=1000,
// op11=(a|~b)=1011, op15=ONE=1111).
// Mux form: r = sel(A, sel(B,m3,m2), sel(B,m1,m0)), sel -> v_bfi_b32.
__device__ __forceinline__ uint64_t bsel64(uint64_t x, uint64_t p, uint64_t q) {
    return (x & p) | (~x & q);
}
__device__ __forceinline__ uint64_t gate64(uint64_t A, uint64_t B, int op) {
    uint64_t m3 = (uint64_t)0 - (uint64_t)((op >> 0) & 1);
    uint64_t m2 = (uint64_t)0 - (uint64_t)((op >> 1) & 1);
    uint64_t m1 = (uint64_t)0 - (uint64_t)((op >> 2) & 1);
    uint64_t m0 = (uint64_t)0 - (uint64_t)((op >> 3) & 1);
    return bsel64(A, bsel64(B, m3, m2), bsel64(B, m1, m0));
}

// ---- 1. Bit-pack via wave ballot: lane <-> batch row, so
//      __ballot(x != 0) IS the packed 64-bit word. One wave per (feature, word).
//      6144 waves = 1536 blocks (was 24 blocks with a 64-load serial loop).
//      Also zeroes d_out (harness re-poisons it to 0xAA before every call). ----
__global__ __launch_bounds__(256) void pack_kernel(const float* __restrict__ x,
                                                   uint64_t* __restrict__ xb,
                                                   float* __restrict__ out) {
    int gt = blockIdx.x * 256 + threadIdx.x;
    if (gt < NB * NCLS) out[gt] = 0.0f;          // fused output zeroing
    int fw = gt >> 6;                            // wave id 0..6143
    int lane = gt & 63;
    int f = fw >> 1, w = fw & 1;
    float val = x[(size_t)(w * 64 + lane) * NFEAT + f];
    uint64_t m = __ballot(val != 0.0f);          // bit i = lane i = batch w*64+i
    if (lane == 0) xb[f * NWORD + w] = m;
}

// ---- 2. Conv logic layer + 3-level tree reduce -> z[KP][NWORD] ----
// Word-split: 2 threads per (k,p), one 64-bit batch word each. 100352 threads
// in 392 blocks (was 196) -> 1568 waves, double the latency-hiding. LDS holds
// the full 48 KB bit table (operand indices span all 3072 features).
__global__ __launch_bounds__(256) void conv_kernel(
    const uint64_t* __restrict__ xb,
    const int* __restrict__ cl, const int* __restrict__ cr,
    const int* __restrict__ o0, const int* __restrict__ o1,
    const int* __restrict__ o2, const int* __restrict__ o3,
    uint64_t* __restrict__ z) {
    __shared__ uint64_t sxb[NFEAT * NWORD];   // 48 KB bit table
    {   // 16B staging: 3072 ulonglong2 entries / 256 threads = 12 iterations
        ulonglong2* s2 = reinterpret_cast<ulonglong2*>(sxb);
        const ulonglong2* g2 = reinterpret_cast<const ulonglong2*>(xb);
        for (int i = threadIdx.x; i < NFEAT; i += blockDim.x)
            s2[i] = g2[i];
    }
    __syncthreads();

    int tid = blockIdx.x * 256 + threadIdx.x;   // 0..100351, exact
    int item = tid >> 1;                        // (k,p) index
    int w = tid & 1;                            // batch word
    int k = item / NP;

    // 8 left + 8 right indices as four int4 loads (pair-redundant, L1-hot)
    const int4* cl4 = reinterpret_cast<const int4*>(cl + (size_t)item * NG);
    const int4* cr4 = reinterpret_cast<const int4*>(cr + (size_t)item * NG);
    int4 l0 = cl4[0], l1 = cl4[1];
    int4 r0 = cr4[0], r1 = cr4[1];
    int la[NG] = {l0.x, l0.y, l0.z, l0.w, l1.x, l1.y, l1.z, l1.w};
    int rb[NG] = {r0.x, r0.y, r0.z, r0.w, r1.x, r1.y, r1.z, r1.w};

    // Hoist all op indices (L1-hot, wave-uniform per k)
    int op0[NG], op1[4], op2[2], op3;
#pragma unroll
    for (int g = 0; g < NG; ++g) op0[g] = o0[k * NG + g];
#pragma unroll
    for (int g = 0; g < 4; ++g) op1[g] = o1[k * 4 + g];
#pragma unroll
    for (int g = 0; g < 2; ++g) op2[g] = o2[k * 2 + g];
    op3 = o3[k];

    uint64_t gg[NG];
#pragma unroll
    for (int g = 0; g < NG; ++g)               // 16 random ds_read_b64
        gg[g] = gate64(sxb[la[g] * NWORD + w], sxb[rb[g] * NWORD + w], op0[g]);
#pragma unroll
    for (int g = 0; g < 4; ++g)
        gg[g] = gate64(gg[2 * g], gg[2 * g + 1], op1[g]);
#pragma unroll
    for (int g = 0; g < 2; ++g)
        gg[g] = gate64(gg[2 * g], gg[2 * g + 1], op2[g]);
    z[(size_t)item * NWORD + w] = gate64(gg[0], gg[1], op3);  // pair-coalesced 16B
}

// ---- 3. Fused lin1+lin2+GroupSum, word-split.
// lin2 makes NL2*2 = 64000 references into the NL1 = 64000-entry z1 table —
// exactly 1.0 average use per element, so recomputing z1 on the fly costs the
// SAME number of gate evals and deletes the 2 MB z1 round-trip + one launch.
// 256-thread blocks = 128 j's x 2 words -> 1000 waves (was 500).
// Phase 2: 128 batch threads x 2 j-halves; broadcast LDS reads; 2 exact
// float atomics per (b,c) per block (counts are small ints -> exact).
__global__ __launch_bounds__(256) void lin2_fused_kernel(
    const uint64_t* __restrict__ z,
    const int* __restrict__ a1, const int* __restrict__ b1,
    const int* __restrict__ p1,
    const int* __restrict__ a2, const int* __restrict__ b2,
    const int* __restrict__ p2, float* __restrict__ out) {
    __shared__ alignas(16) uint64_t s[NWORD][JBLK];
    int blk = blockIdx.x;
    const int chunks_per_cls = (NL2 / NCLS) / JBLK;   // 25
    int c = blk / chunks_per_cls;

    int jloc = threadIdx.x >> 1;
    int w = threadIdx.x & 1;
    int j = c * (NL2 / NCLS) + (blk % chunks_per_cls) * JBLK + jloc;

    int ia = a2[j], ib = b2[j], op = p2[j];
    // z1[ia], z1[ib] recomputed from the conv output table z (word w only)
    uint64_t za = gate64(z[(size_t)a1[ia] * NWORD + w], z[(size_t)b1[ia] * NWORD + w], p1[ia]);
    uint64_t zb = gate64(z[(size_t)a1[ib] * NWORD + w], z[(size_t)b1[ib] * NWORD + w], p1[ib]);
    s[w][jloc] = gate64(za, zb, op);   // pair writes -> 2-way bank alias (free)
    __syncthreads();

    int bb = threadIdx.x & 127;        // batch index 0..127
    int half = threadIdx.x >> 7;       // which 64-j half
    int wq = bb >> 6, sh = bb & 63;
    const ulonglong2* sp = reinterpret_cast<const ulonglong2*>(s[wq]) + half * (JBLK / 4);
    int cnt = 0;
#pragma unroll
    for (int jj = 0; jj < JBLK / 4; ++jj) {
        ulonglong2 v = sp[jj];         // wave-broadcast (all lanes same address)
        cnt += (int)((v.x >> sh) & 1) + (int)((v.y >> sh) & 1);
    }
    atomicAdd(&out[bb * NCLS + c], (float)cnt);
}

extern "C" void kernel_launch(void* const* d_in, const int* in_sizes, int n_in,
                              void* d_out, int out_size, void* d_ws, size_t ws_size,
                              hipStream_t stream) {
    const float* x  = (const float*)d_in[0];
    const int* cl   = (const int*)d_in[1];
    const int* cr   = (const int*)d_in[2];
    const int* o0   = (const int*)d_in[3];
    const int* o1   = (const int*)d_in[4];
    const int* o2   = (const int*)d_in[5];
    const int* o3   = (const int*)d_in[6];
    const int* a1   = (const int*)d_in[7];
    const int* b1   = (const int*)d_in[8];
    const int* p1   = (const int*)d_in[9];
    const int* a2   = (const int*)d_in[10];
    const int* b2   = (const int*)d_in[11];
    const int* p2   = (const int*)d_in[12];
    float* out = (float*)d_out;

    uint8_t* ws = (uint8_t*)d_ws;
    uint64_t* xb = (uint64_t*)(ws);                                   // 48 KB
    uint64_t* z  = (uint64_t*)(ws + 64 * 1024);                       // 784 KB

    // pack: 6144 waves = 1536 blocks (exactly NFEAT*NWORD waves, no tail)
    pack_kernel<<<(NFEAT * NWORD * 64) / 256, 256, 0, stream>>>(x, xb, out);
    // conv: 100352 threads = 392 blocks (exact)
    conv_kernel<<<(KP * NWORD) / 256, 256, 0, stream>>>(xb, cl, cr, o0, o1, o2, o3, z);
    // lin1+lin2+sum: 250 blocks x 256 threads
    lin2_fused_kernel<<<NL2 / JBLK, 256, 0, stream>>>(z, a1, b1, p1, a2, b2, p2, out);
}

// Round 10
// 97.224 us; speedup vs baseline: 1.0763x; 1.0763x over previous
//
#include <hip/hip_runtime.h>
#include <stdint.h>

// Problem constants (match reference)
#define NFEAT 3072          // C*H*W
#define NWORD 2             // 128 batch bits / 64
#define NK 64               // kernels
#define NP 784              // output positions
#define NG 8                // level-0 gates per (k,p)
#define KP (NK * NP)        // 50176
#define NL1 64000
#define NL2 32000
#define NCLS 10
#define NB 128              // batch
#define JBLK 128            // j's per lin2 block; 3200 % 128 == 0

// Truth-table gate. op bit0 -> (a=1,b=1), bit1 -> (a=1,b=0), bit2 -> (a=0,b=1),
// bit3 -> (a=0,b=0). Verified against ALL 16 COEF rows: the op index's binary
// representation IS the truth table (op1=AND=0001, op6=XOR=0110, op8=NOR=1000,
// op11=(a|~b)=1011, op15=ONE=1111).
// Mux form: r = sel(A, sel(B,m3,m2), sel(B,m1,m0)), sel -> v_bfi_b32.
__device__ __forceinline__ uint64_t bsel64(uint64_t x, uint64_t p, uint64_t q) {
    return (x & p) | (~x & q);
}
__device__ __forceinline__ ulonglong2 gate128(ulonglong2 A, ulonglong2 B, int op) {
    uint64_t m3 = (uint64_t)0 - (uint64_t)((op >> 0) & 1);
    uint64_t m2 = (uint64_t)0 - (uint64_t)((op >> 1) & 1);
    uint64_t m1 = (uint64_t)0 - (uint64_t)((op >> 2) & 1);
    uint64_t m0 = (uint64_t)0 - (uint64_t)((op >> 3) & 1);
    ulonglong2 r;
    r.x = bsel64(A.x, bsel64(B.x, m3, m2), bsel64(B.x, m1, m0));
    r.y = bsel64(A.y, bsel64(B.y, m3, m2), bsel64(B.y, m1, m0));
    return r;
}

// ---- 1. Bit-pack via wave ballot: lane <-> batch row, so __ballot(x != 0)
//      IS the packed 64-bit word. One wave per (feature, word); 1536 blocks.
//      Also zeroes d_out (harness re-poisons it to 0xAA before every call). ----
__global__ __launch_bounds__(256) void pack_kernel(const float* __restrict__ x,
                                                   uint64_t* __restrict__ xb,
                                                   float* __restrict__ out) {
    int gt = blockIdx.x * 256 + threadIdx.x;
    if (gt < NB * NCLS) out[gt] = 0.0f;          // fused output zeroing
    int fw = gt >> 6;                            // wave id 0..6143
    int lane = gt & 63;
    int f = fw >> 1, w = fw & 1;
    float val = x[(size_t)(w * 64 + lane) * NFEAT + f];
    uint64_t m = __ballot(val != 0.0f);          // bit i = lane i = batch w*64+i
    if (lane == 0) xb[f * NWORD + w] = m;
}

// ---- 2. Conv logic layer + 3-level tree reduce -> z[KP][NWORD] ----
// One thread per (k,p), both batch words (ILP-2 in .x/.y): 196 blocks.
// 16B ds_read per operand, ONE int4-pair index load per item (round-6's
// word-split duplicated index traffic and halved gather width -> regressed).
__global__ __launch_bounds__(256) void conv_kernel(
    const uint64_t* __restrict__ xb,
    const int* __restrict__ cl, const int* __restrict__ cr,
    const int* __restrict__ o0, const int* __restrict__ o1,
    const int* __restrict__ o2, const int* __restrict__ o3,
    uint64_t* __restrict__ z) {
    __shared__ uint64_t sxb[NFEAT * NWORD];   // 48 KB bit table
    {   // 16B staging: 3072 ulonglong2 entries / 256 threads = 12 iterations
        ulonglong2* s2 = reinterpret_cast<ulonglong2*>(sxb);
        const ulonglong2* g2 = reinterpret_cast<const ulonglong2*>(xb);
        for (int i = threadIdx.x; i < NFEAT; i += blockDim.x)
            s2[i] = g2[i];
    }
    __syncthreads();

    int t = blockIdx.x * 256 + threadIdx.x;
    if (t >= KP) return;
    int k = t / NP;

    // 8 left + 8 right indices as four int4 loads (32B contiguous per thread)
    const int4* cl4 = reinterpret_cast<const int4*>(cl + (size_t)t * NG);
    const int4* cr4 = reinterpret_cast<const int4*>(cr + (size_t)t * NG);
    int4 l0 = cl4[0], l1 = cl4[1];
    int4 r0 = cr4[0], r1 = cr4[1];
    int la[NG] = {l0.x, l0.y, l0.z, l0.w, l1.x, l1.y, l1.z, l1.w};
    int rb[NG] = {r0.x, r0.y, r0.z, r0.w, r1.x, r1.y, r1.z, r1.w};

    // Hoist all op indices (L1-hot, wave-uniform per k)
    int op0[NG], op1[4], op2[2], op3;
#pragma unroll
    for (int g = 0; g < NG; ++g) op0[g] = o0[k * NG + g];
#pragma unroll
    for (int g = 0; g < 4; ++g) op1[g] = o1[k * 4 + g];
#pragma unroll
    for (int g = 0; g < 2; ++g) op2[g] = o2[k * 2 + g];
    op3 = o3[k];

    const ulonglong2* sxb2 = reinterpret_cast<const ulonglong2*>(sxb);
    ulonglong2 gg[NG];
#pragma unroll
    for (int g = 0; g < NG; ++g) {
        ulonglong2 va = sxb2[la[g]];           // one ds_read_b128 per operand
        ulonglong2 vb = sxb2[rb[g]];
        gg[g] = gate128(va, vb, op0[g]);
    }
#pragma unroll
    for (int g = 0; g < 4; ++g)
        gg[g] = gate128(gg[2 * g], gg[2 * g + 1], op1[g]);
#pragma unroll
    for (int g = 0; g < 2; ++g)
        gg[g] = gate128(gg[2 * g], gg[2 * g + 1], op2[g]);
    reinterpret_cast<ulonglong2*>(z)[t] = gate128(gg[0], gg[1], op3);
}

// ---- 3. Fused lin1+lin2+GroupSum.
// lin2 makes NL2*2 = 64000 references into the NL1 = 64000-entry z1 table —
// exactly 1.0 average use per element, so recomputing z1 on the fly costs the
// SAME number of gate evals and deletes the 2 MB z1 round-trip + one launch.
// One block per (class, 128-j chunk); one thread per j, both words (ILP-2,
// 16B gathers, one index set per j). Phase 2: thread bb extracts bit bb
// across the 128 j's via 64 broadcast ds_read_b128 and atomically adds into
// out[bb][c]. Counts are small ints -> float atomicAdd exact, order-free.
__global__ __launch_bounds__(JBLK) void lin2_fused_kernel(
    const uint64_t* __restrict__ z,
    const int* __restrict__ a1, const int* __restrict__ b1,
    const int* __restrict__ p1,
    const int* __restrict__ a2, const int* __restrict__ b2,
    const int* __restrict__ p2, float* __restrict__ out) {
    __shared__ alignas(16) uint64_t s[NWORD][JBLK];
    int blk = blockIdx.x;
    const int chunks_per_cls = (NL2 / NCLS) / JBLK;   // 25
    int c = blk / chunks_per_cls;
    int j = c * (NL2 / NCLS) + (blk % chunks_per_cls) * JBLK + threadIdx.x;

    int ia = a2[j], ib = b2[j], op = p2[j];
    // z1[ia], z1[ib] recomputed from the conv output table z
    int iaa = a1[ia], iab = b1[ia], opa = p1[ia];
    int iba = a1[ib], ibb = b1[ib], opb = p1[ib];
    const ulonglong2* z2p = reinterpret_cast<const ulonglong2*>(z);
    ulonglong2 za = gate128(z2p[iaa], z2p[iab], opa);
    ulonglong2 zb = gate128(z2p[iba], z2p[ibb], opb);
    ulonglong2 zz = gate128(za, zb, op);
    s[0][threadIdx.x] = zz.x;
    s[1][threadIdx.x] = zz.y;
    __syncthreads();

    int bb = threadIdx.x;          // batch index 0..127
    int w = bb >> 6, sh = bb & 63;
    const ulonglong2* sp = reinterpret_cast<const ulonglong2*>(s[w]);
    int cnt = 0;
#pragma unroll 16
    for (int jj = 0; jj < JBLK / 2; ++jj) {
        ulonglong2 v = sp[jj];     // wave-broadcast (all lanes same address)
        cnt += (int)((v.x >> sh) & 1) + (int)((v.y >> sh) & 1);
    }
    atomicAdd(&out[bb * NCLS + c], (float)cnt);
}

extern "C" void kernel_launch(void* const* d_in, const int* in_sizes, int n_in,
                              void* d_out, int out_size, void* d_ws, size_t ws_size,
                              hipStream_t stream) {
    const float* x  = (const float*)d_in[0];
    const int* cl   = (const int*)d_in[1];
    const int* cr   = (const int*)d_in[2];
    const int* o0   = (const int*)d_in[3];
    const int* o1   = (const int*)d_in[4];
    const int* o2   = (const int*)d_in[5];
    const int* o3   = (const int*)d_in[6];
    const int* a1   = (const int*)d_in[7];
    const int* b1   = (const int*)d_in[8];
    const int* p1   = (const int*)d_in[9];
    const int* a2   = (const int*)d_in[10];
    const int* b2   = (const int*)d_in[11];
    const int* p2   = (const int*)d_in[12];
    float* out = (float*)d_out;

    uint8_t* ws = (uint8_t*)d_ws;
    uint64_t* xb = (uint64_t*)(ws);                                   // 48 KB
    uint64_t* z  = (uint64_t*)(ws + 64 * 1024);                       // 784 KB

    // pack: 6144 waves = 1536 blocks (exactly NFEAT*NWORD waves, no tail)
    pack_kernel<<<(NFEAT * NWORD * 64) / 256, 256, 0, stream>>>(x, xb, out);
    // conv: 50176 threads -> 196 blocks
    conv_kernel<<<(KP + 255) / 256, 256, 0, stream>>>(xb, cl, cr, o0, o1, o2, o3, z);
    // lin1+lin2+sum: 250 blocks x 128 threads
    lin2_fused_kernel<<<NL2 / JBLK, JBLK, 0, stream>>>(z, a1, b1, p1, a2, b2, p2, out);
}